// Round 16
// baseline (273.728 us; speedup 1.0000x reference)
//
#include <hip/hip_runtime.h>

// LightGCN on MI355X — round 26.
//  * partition: EWG 6272->3136 (1022 wgs, half the per-wg serial chain)
//    + NREP 4->8 (contention stays 128/addr = R14's proven level; per-cell
//    fill 1024+-32 vs RSTR 1280 = 8-sigma margin) + LDS 46.9->28KB ->
//    5 blocks/CU, all 1022 wgs resident (~4/CU vs 2/CU before).
//    = R12's parallelism without R12's two regressions (tcur serialization,
//    LDS-capped residency).
//  * build reads 8 replica lengths (2x int4); otherwise R25-identical.
//  * spmm_sum / score / build body byte-identical to R25 (262.7us best).
// 6 launches: memset, partition, build+y0, spmm, spmm, score.

#define DIM 64
#define TSHIFT 8
#define TMASK ((1 << TSHIFT) - 1)
#define TPAD 768
#define EWG 3136
#define STAGE_CAP 3136
#define NREP 8
#define RSTR 1280
#define TSTRIDE 10240
#define NI4 4  // ceil((EWG/4)/256) int4 slots per thread

typedef unsigned short u16;
typedef unsigned char u8;
typedef unsigned int u32;
typedef unsigned int uv4 __attribute__((ext_vector_type(4)));
typedef float f2 __attribute__((ext_vector_type(2)));

__device__ __forceinline__ u32 f2bf(float f) {  // RNE pack to bf16 bits
  u32 u = __float_as_uint(f);
  return (u + 0x7FFFu + ((u >> 16) & 1u)) >> 16;
}
__device__ __forceinline__ float bflo(u32 u) {
  return __uint_as_float(u << 16);
}
__device__ __forceinline__ float bfhi(u32 u) {
  return __uint_as_float(u & 0xFFFF0000u);
}
__device__ __forceinline__ f2 up2(u32 u) {
  f2 r;
  r.x = bflo(u);
  r.y = bfhi(u);
  return r;
}

// inclusive scan of lsum across 256 threads; wsum is 4-entry LDS scratch.
__device__ __forceinline__ int block_incl_scan(int lsum, int tid, int* wsum) {
  int lane = tid & 63, wv = tid >> 6;
  int v = lsum;
#pragma unroll
  for (int off = 1; off < 64; off <<= 1) {
    int t = __shfl_up(v, off, 64);
    if (lane >= off) v += t;
  }
  __syncthreads();
  if (lane == 63) wsum[wv] = v;
  __syncthreads();
  int add = 0;
  if (wv > 0) add += wsum[0];
  if (wv > 1) add += wsum[1];
  if (wv > 2) add += wsum[2];
  return v + add;
}

// ---------------- single-pass tile partition into padded bucket ------------

__global__ __launch_bounds__(256) void partition_direct(
    const int* __restrict__ rows, const int* __restrict__ cols, int nnz,
    int T, int* __restrict__ tcur, u32* __restrict__ bucket) {
  __shared__ u32 sorted[STAGE_CAP];
  __shared__ u16 sortedt[STAGE_CAP];
  __shared__ int cnt[TPAD], lstart[TPAD], gbase[TPAD];
  __shared__ int wsum[4];
  int w = blockIdx.x, tid = threadIdx.x;
  int rep = w & (NREP - 1);
  int j0 = tid * 3;
  cnt[j0] = 0; cnt[j0 + 1] = 0; cnt[j0 + 2] = 0;
  __syncthreads();
  int base = w * EWG;
  int end = min(base + EWG, nnz);
  int total = end - base;
  if (total <= 0) return;
  int nv = total >> 2;
  const int4* r4 = (const int4*)(rows + base);
  const int4* c4 = (const int4*)(cols + base);
  // pass 1: histogram rows; cache row int4s in registers for pass 2
  int4 rr[NI4];
#pragma unroll
  for (int j = 0; j < NI4; ++j) {
    int i = tid + j * 256;
    if (i < nv) {
      int4 r = r4[i];
      rr[j] = r;
      atomicAdd(&cnt[r.x >> TSHIFT], 1);
      atomicAdd(&cnt[r.y >> TSHIFT], 1);
      atomicAdd(&cnt[r.z >> TSHIFT], 1);
      atomicAdd(&cnt[r.w >> TSHIFT], 1);
    }
  }
  for (int e = base + (nv << 2) + tid; e < end; e += 256)
    atomicAdd(&cnt[rows[e] >> TSHIFT], 1);
  __syncthreads();
  int c0 = cnt[j0], c1 = cnt[j0 + 1], c2 = cnt[j0 + 2];
  int lsum = c0 + c1 + c2;
  int incl = block_incl_scan(lsum, tid, wsum);
  int excl = incl - lsum;
  lstart[j0] = excl;
  lstart[j0 + 1] = excl + c0;
  lstart[j0 + 2] = excl + c0 + c1;
  if (c0 > 0)
    gbase[j0] = j0 * TSTRIDE + rep * RSTR + atomicAdd(&tcur[j0 * NREP + rep], c0);
  if (c1 > 0)
    gbase[j0 + 1] = (j0 + 1) * TSTRIDE + rep * RSTR +
                    atomicAdd(&tcur[(j0 + 1) * NREP + rep], c1);
  if (c2 > 0)
    gbase[j0 + 2] = (j0 + 2) * TSTRIDE + rep * RSTR +
                    atomicAdd(&tcur[(j0 + 2) * NREP + rep], c2);
  cnt[j0] = 0; cnt[j0 + 1] = 0; cnt[j0 + 2] = 0;
  __syncthreads();
  // pass 2: rows from registers, cols from memory
#pragma unroll
  for (int j = 0; j < NI4; ++j) {
    int i = tid + j * 256;
    if (i < nv) {
      int4 r = rr[j];
      int4 c = c4[i];
      int t, s, d;
      t = r.x >> TSHIFT; s = atomicAdd(&cnt[t], 1); d = lstart[t] + s;
      sorted[d] = ((u32)(r.x & TMASK) << 18) | (u32)c.x; sortedt[d] = (u16)t;
      t = r.y >> TSHIFT; s = atomicAdd(&cnt[t], 1); d = lstart[t] + s;
      sorted[d] = ((u32)(r.y & TMASK) << 18) | (u32)c.y; sortedt[d] = (u16)t;
      t = r.z >> TSHIFT; s = atomicAdd(&cnt[t], 1); d = lstart[t] + s;
      sorted[d] = ((u32)(r.z & TMASK) << 18) | (u32)c.z; sortedt[d] = (u16)t;
      t = r.w >> TSHIFT; s = atomicAdd(&cnt[t], 1); d = lstart[t] + s;
      sorted[d] = ((u32)(r.w & TMASK) << 18) | (u32)c.w; sortedt[d] = (u16)t;
    }
  }
  for (int e = base + (nv << 2) + tid; e < end; e += 256) {
    int r = rows[e];
    int c = cols[e];
    int t = r >> TSHIFT;
    int s = atomicAdd(&cnt[t], 1);
    int d = lstart[t] + s;
    sorted[d] = ((u32)(r & TMASK) << 18) | (u32)c;
    sortedt[d] = (u16)t;
  }
  __syncthreads();
  for (int i = tid; i < total; i += 256) {
    int t = sortedt[i];
    bucket[(size_t)gbase[t] + (i - lstart[t])] = sorted[i];
  }
}

// ---------------- build: one block per 256-row tile, LDS-cached bucket -----

__global__ __launch_bounds__(256) void build_csr_y0(
    const u32* __restrict__ bucket, const int* __restrict__ tcur, int T,
    int U, int N, const float4* __restrict__ ue, const float4* __restrict__ ie,
    int* __restrict__ row_ptr, u32* __restrict__ csr,
    uint4* __restrict__ y0b) {
  __shared__ u32 ebuf[TSTRIDE];  // tile entries, compacted (<= 10240)
  __shared__ int tl[TPAD];
  __shared__ int hist[256];
  __shared__ int cur[256];
  __shared__ int wsum[4];
  int b = blockIdx.x;
  int t = (b & 1) ? (T - 1 - (b >> 1)) : (b >> 1);
  int tid = threadIdx.x;
  int j0 = tid * 3;
  int v0 = 0, v1 = 0, v2 = 0;
  if (j0 < T) {
    int4 qa = ((const int4*)tcur)[j0 * 2];
    int4 qb = ((const int4*)tcur)[j0 * 2 + 1];
    v0 = qa.x + qa.y + qa.z + qa.w + qb.x + qb.y + qb.z + qb.w;
  }
  if (j0 + 1 < T) {
    int4 qa = ((const int4*)tcur)[(j0 + 1) * 2];
    int4 qb = ((const int4*)tcur)[(j0 + 1) * 2 + 1];
    v1 = qa.x + qa.y + qa.z + qa.w + qb.x + qb.y + qb.z + qb.w;
  }
  if (j0 + 2 < T) {
    int4 qa = ((const int4*)tcur)[(j0 + 2) * 2];
    int4 qb = ((const int4*)tcur)[(j0 + 2) * 2 + 1];
    v2 = qa.x + qa.y + qa.z + qa.w + qb.x + qb.y + qb.z + qb.w;
  }
  int lsum = v0 + v1 + v2;
  int incl0 = block_incl_scan(lsum, tid, wsum);
  int excl0 = incl0 - lsum;
  tl[j0] = excl0 + v0;
  tl[j0 + 1] = excl0 + v0 + v1;
  tl[j0 + 2] = excl0 + v0 + v1 + v2;
  hist[tid] = 0;
  __syncthreads();
  int tbase = (t == 0) ? 0 : tl[t - 1];
  // single global pass: histogram + compact tile into LDS ebuf
  int off = 0;
#pragma unroll
  for (int rep = 0; rep < NREP; ++rep) {
    int len = tcur[t * NREP + rep];
    int rs = t * TSTRIDE + rep * RSTR;
    const uint4* b4 = (const uint4*)(bucket + rs);
    int nv = len >> 2;
    for (int i = tid; i < nv; i += 256) {
      uint4 e = b4[i];
      int d = off + (i << 2);
      ebuf[d] = e.x; ebuf[d + 1] = e.y; ebuf[d + 2] = e.z; ebuf[d + 3] = e.w;
      atomicAdd(&hist[e.x >> 18], 1);
      atomicAdd(&hist[e.y >> 18], 1);
      atomicAdd(&hist[e.z >> 18], 1);
      atomicAdd(&hist[e.w >> 18], 1);
    }
    for (int i = (nv << 2) + tid; i < len; i += 256) {
      u32 e = bucket[rs + i];
      ebuf[off + i] = e;
      atomicAdd(&hist[e >> 18], 1);
    }
    off += len;
  }
  int tlen = off;
  __syncthreads();
  int h = hist[tid];
  int incl = block_incl_scan(h, tid, wsum);
  int r = (t << TSHIFT) + tid;
  if (r < N) row_ptr[r + 1] = tbase + incl;
  if (t == 0 && tid == 0) row_ptr[0] = 0;
  if (b == 0 && tid < 8)  // zero sentinel row of y0b (spmm1 pads with it)
    y0b[(size_t)N * 8 + tid] = make_uint4(0, 0, 0, 0);
  cur[tid] = tbase + incl - h;
  __syncthreads();
  for (int pass = 0; pass < 8; ++pass) {
    int lr = pass * 32 + (tid >> 3);
    int q = tid & 7;
    int row = (t << TSHIFT) + lr;
    if (row < N) {
      float invs = rsqrtf((float)max(hist[lr], 1));
      const float4* src = (row < U) ? (ue + (size_t)row * 16 + q * 2)
                                    : (ie + (size_t)(row - U) * 16 + q * 2);
      float4 a = src[0], bb = src[1];
      uint4 o;
      o.x = f2bf(a.x * invs) | (f2bf(a.y * invs) << 16);
      o.y = f2bf(a.z * invs) | (f2bf(a.w * invs) << 16);
      o.z = f2bf(bb.x * invs) | (f2bf(bb.y * invs) << 16);
      o.w = f2bf(bb.z * invs) | (f2bf(bb.w * invs) << 16);
      y0b[(size_t)row * 8 + q] = o;
    }
  }
  // scatter entries into compact csr, from LDS
  for (int i = tid; i < tlen; i += 256) {
    u32 e = ebuf[i];
    csr[atomicAdd(&cur[e >> 18], 1)] = e & 0x3FFFFu;
  }
}

// ---------------- SpMM: 1 row / 8-lane group, 2-stage pipelined gathers ----

__device__ __forceinline__ void load_stage(
    u32 (&c)[8], uv4 (&g)[8], int k, int d, int s,
    const u32* __restrict__ csr, const char* __restrict__ yb, u32 soff,
    int n) {
#pragma unroll
  for (int j = 0; j < 8; ++j) c[j] = (k + j < d) ? csr[s + k + j] : (u32)n;
#pragma unroll
  for (int j = 0; j < 8; ++j)
    g[j] = *(const uv4*)(yb + (size_t)(((size_t)c[j] << 7) | soff));
}

#define ACC_STAGE(G)                                                         \
  _Pragma("unroll") for (int j = 0; j < 8; ++j) {                            \
    a0 += up2(G[j].x);                                                       \
    a1 += up2(G[j].y);                                                       \
    a2 += up2(G[j].z);                                                       \
    a3 += up2(G[j].w);                                                       \
  }

__global__ __launch_bounds__(256, 4) void spmm_sum(
    const int* __restrict__ row_ptr, const u32* __restrict__ csr,
    const u16* __restrict__ yin, u16* __restrict__ yout, int n) {
  if (blockIdx.x == 0 && threadIdx.x < 8)  // zero sentinel row of output
    ((uint4*)(yout + (size_t)n * DIM))[threadIdx.x] = make_uint4(0, 0, 0, 0);
  int row = (blockIdx.x * 256 + threadIdx.x) >> 3;
  int q8 = threadIdx.x & 7;
  if (row >= n) return;
  int s = row_ptr[row];
  int d = row_ptr[row + 1] - s;
  const char* yb = (const char*)yin;
  u32 soff = (u32)q8 << 4;
  f2 a0 = 0.f, a1 = 0.f, a2 = 0.f, a3 = 0.f;
  u32 cA[8], cB[8];
  uv4 gA[8], gB[8];
  if (d > 0) {
    load_stage(cA, gA, 0, d, s, csr, yb, soff, n);
    int k = 8;
    while (k < d) {
      load_stage(cB, gB, k, d, s, csr, yb, soff, n);
      k += 8;
      ACC_STAGE(gA)
      if (k >= d) {
        ACC_STAGE(gB)
        goto done;
      }
      load_stage(cA, gA, k, d, s, csr, yb, soff, n);
      k += 8;
      ACC_STAGE(gB)
    }
    ACC_STAGE(gA)
  }
done:;
  float inv = 1.0f / (float)max(d, 1);
  uint4 o;
  o.x = f2bf(a0.x * inv) | (f2bf(a0.y * inv) << 16);
  o.y = f2bf(a1.x * inv) | (f2bf(a1.y * inv) << 16);
  o.z = f2bf(a2.x * inv) | (f2bf(a2.y * inv) << 16);
  o.w = f2bf(a3.x * inv) | (f2bf(a3.y * inv) << 16);
  ((uint4*)(yout + (size_t)row * DIM))[q8] = o;
}

// ---------------- fused layer-3 + scorer (R21 one-wave-per-gather) ---------

#define ACC8(G)                                                              \
  s0 += bflo(G.x); s1 += bfhi(G.x);                                          \
  s2 += bflo(G.y); s3 += bfhi(G.y);                                          \
  s4 += bflo(G.z); s5 += bfhi(G.z);                                          \
  s6 += bflo(G.w); s7 += bfhi(G.w);

__device__ __forceinline__ void gather8(
    const int* __restrict__ row_ptr, const u32* __restrict__ csr,
    const u16* __restrict__ y, int row, int s, int q8, int n, float* o) {
  int start = row_ptr[row];
  int end = row_ptr[row + 1];
  float s0 = 0.f, s1 = 0.f, s2 = 0.f, s3 = 0.f;
  float s4 = 0.f, s5 = 0.f, s6 = 0.f, s7 = 0.f;
  for (int k = start + s; k < end; k += 16) {
    int k2 = k + 8;
    bool ok2 = k2 < end;
    u32 c0 = csr[k];
    u32 c1 = ok2 ? csr[k2] : (u32)n;
    uint4 g0 = ((const uint4*)(y + (size_t)c0 * DIM))[q8];
    uint4 g1 = ((const uint4*)(y + (size_t)c1 * DIM))[q8];
    ACC8(g0) ACC8(g1)
  }
  for (int m = 8; m <= 32; m <<= 1) {
    s0 += __shfl_xor(s0, m, 64); s1 += __shfl_xor(s1, m, 64);
    s2 += __shfl_xor(s2, m, 64); s3 += __shfl_xor(s3, m, 64);
    s4 += __shfl_xor(s4, m, 64); s5 += __shfl_xor(s5, m, 64);
    s6 += __shfl_xor(s6, m, 64); s7 += __shfl_xor(s7, m, 64);
  }
  o[0] = s0; o[1] = s1; o[2] = s2; o[3] = s3;
  o[4] = s4; o[5] = s5; o[6] = s6; o[7] = s7;
}

// 2 pairs/block; 2 waves/pair (wave0=user row, wave1=item row). Each wave
// builds its side's full 64-dim vector into LDS; wave0 does the dot.
__global__ __launch_bounds__(256) void spmm3_score(
    const int* __restrict__ row_ptr, const u32* __restrict__ csr,
    const float* __restrict__ ue, const float* __restrict__ ie,
    const u16* __restrict__ y1b, const u16* __restrict__ y2b,
    const int* __restrict__ user_ids, const int* __restrict__ item_ids,
    int U, int N, int batch, float* __restrict__ out) {
  __shared__ float ab[2][2][64];  // [pair-in-block][side][dim]
  int tid = threadIdx.x;
  int pl = tid >> 7;              // pair slot in block (0,1)
  int side = (tid >> 6) & 1;      // 0=user, 1=item
  int lane = tid & 63;
  int w = blockIdx.x * 2 + pl;
  bool active = w < batch;
  int s = lane >> 3;
  int q8 = lane & 7;
  if (active) {
    int u = user_ids[w];
    int iti = item_ids[w];
    int row = (side == 0) ? u : iti + U;
    float g[8];
    gather8(row_ptr, csr, y2b, row, s, q8, N, g);
    int dd = row_ptr[row + 1] - row_ptr[row];
    float sd = sqrtf((float)max(dd, 1)), rd = 1.0f / sd;
    const float4* pe = (side == 0)
                           ? (const float4*)(ue + (size_t)u * DIM) + q8 * 2
                           : (const float4*)(ie + (size_t)iti * DIM) + q8 * 2;
    float4 ea = pe[0], eb = pe[1];
    uint4 y1v = ((const uint4*)(y1b + (size_t)row * DIM))[q8];
    uint4 y2v = ((const uint4*)(y2b + (size_t)row * DIM))[q8];
    if (s == 0) {  // one writer per q8 (all s-lanes hold identical g)
      float* dst = &ab[pl][side][q8 * 8];
      dst[0] = ea.x + sd * (bflo(y1v.x) + bflo(y2v.x)) + rd * g[0];
      dst[1] = ea.y + sd * (bfhi(y1v.x) + bfhi(y2v.x)) + rd * g[1];
      dst[2] = ea.z + sd * (bflo(y1v.y) + bflo(y2v.y)) + rd * g[2];
      dst[3] = ea.w + sd * (bfhi(y1v.y) + bfhi(y2v.y)) + rd * g[3];
      dst[4] = eb.x + sd * (bflo(y1v.z) + bflo(y2v.z)) + rd * g[4];
      dst[5] = eb.y + sd * (bfhi(y1v.z) + bfhi(y2v.z)) + rd * g[5];
      dst[6] = eb.z + sd * (bflo(y1v.w) + bflo(y2v.w)) + rd * g[6];
      dst[7] = eb.w + sd * (bfhi(y1v.w) + bfhi(y2v.w)) + rd * g[7];
    }
  }
  __syncthreads();
  if (active && side == 0) {
    float p = ab[pl][0][lane] * ab[pl][1][lane];
    p += __shfl_xor(p, 1, 64);
    p += __shfl_xor(p, 2, 64);
    p += __shfl_xor(p, 4, 64);
    p += __shfl_xor(p, 8, 64);
    p += __shfl_xor(p, 16, 64);
    p += __shfl_xor(p, 32, 64);
    if (lane == 0) out[w] = p * (1.0f / 16.0f);
  }
}

extern "C" void kernel_launch(void* const* d_in, const int* in_sizes, int n_in,
                              void* d_out, int out_size, void* d_ws, size_t ws_size,
                              hipStream_t stream) {
  const float* user_emb = (const float*)d_in[0];
  const float* item_emb = (const float*)d_in[1];
  const int* adj_rows = (const int*)d_in[3];
  const int* adj_cols = (const int*)d_in[4];
  const int* user_ids = (const int*)d_in[5];
  const int* item_ids = (const int*)d_in[6];
  float* scores = (float*)d_out;

  const int U = in_sizes[0] / DIM;  // 100000
  const int I = in_sizes[1] / DIM;  // 50000
  const int N = U + I;              // 150000
  const int nnz = in_sizes[2];      // 3200000
  const int B = in_sizes[5];        // 4096

  const int T = (N + TMASK) >> TSHIFT;    // 586
  const int npw = (nnz + EWG - 1) / EWG;  // 1021
  (void)ws_size;

  char* p = (char*)d_ws;
  auto carve = [&](size_t bytes) {
    void* r = (void*)p;
    p += (bytes + 255) & ~(size_t)255;
    return r;
  };
  u16* y0b = (u16*)carve((size_t)(N + 1) * DIM * 2);
  u16* y1b = (u16*)carve((size_t)(N + 1) * DIM * 2);
  u16* y2b = (u16*)carve((size_t)(N + 1) * DIM * 2);
  int* row_ptr = (int*)carve((size_t)(N + 1) * 4);
  int* tcur = (int*)carve((size_t)T * NREP * 4);
  u32* bucket = (u32*)carve((size_t)(T + 1) * TSTRIDE * 4);
  u32* csr = (u32*)carve((size_t)nnz * 4);

  hipMemsetAsync(tcur, 0, (size_t)T * NREP * 4, stream);

  partition_direct<<<npw, 256, 0, stream>>>(adj_rows, adj_cols, nnz, T, tcur,
                                            bucket);

  build_csr_y0<<<T, 256, 0, stream>>>(bucket, tcur, T, U, N,
                                      (const float4*)user_emb,
                                      (const float4*)item_emb, row_ptr,
                                      csr, (uint4*)y0b);

  const int sblocks = (N * 8 + 255) / 256;  // 8 lanes per row
  spmm_sum<<<sblocks, 256, 0, stream>>>(row_ptr, csr, y0b, y1b, N);
  spmm_sum<<<sblocks, 256, 0, stream>>>(row_ptr, csr, y1b, y2b, N);

  spmm3_score<<<(B + 1) / 2, 256, 0, stream>>>(row_ptr, csr, user_emb,
                                               item_emb, y1b, y2b, user_ids,
                                               item_ids, U, N, B, scores);
}

// Round 17
// 261.433 us; speedup vs baseline: 1.0470x; 1.0470x over previous
//
#include <hip/hip_runtime.h>

// LightGCN on MI355X — round 27 (revert to R25, best = 262.7us).
//  * R26 post-mortem: EWG 6272->3136 halved bucket flush run length
//    (10.7->5.4 entries -> ~2x partial-sector write amp) and added per-wg
//    fixed overhead: +11us. EWG=6272/NREP=4 confirmed a local optimum from
//    both directions (R12: 2560 worse, R26: 3136 worse).
//  * Levers closed by counter evidence: spmm at compulsory-fetch floor
//    (R24 occupancy null, R18 ILP marginal, R17 NT harmful); fusion
//    refuted (R22 coop-launch fails under capture, R23 software barriers
//    cost 10x savings); build LDS-cached (R25); score restructured (R21).
// 6 launches: memset, partition, build+y0, spmm, spmm, score.

#define DIM 64
#define TSHIFT 8
#define TMASK ((1 << TSHIFT) - 1)
#define TPAD 768
#define EWG 6272
#define STAGE_CAP 6272
#define NREP 4
#define RSTR 2560
#define TSTRIDE 10240
#define NI4 7  // ceil((EWG/4)/256) int4 slots per thread

typedef unsigned short u16;
typedef unsigned char u8;
typedef unsigned int u32;
typedef unsigned int uv4 __attribute__((ext_vector_type(4)));
typedef float f2 __attribute__((ext_vector_type(2)));

__device__ __forceinline__ u32 f2bf(float f) {  // RNE pack to bf16 bits
  u32 u = __float_as_uint(f);
  return (u + 0x7FFFu + ((u >> 16) & 1u)) >> 16;
}
__device__ __forceinline__ float bflo(u32 u) {
  return __uint_as_float(u << 16);
}
__device__ __forceinline__ float bfhi(u32 u) {
  return __uint_as_float(u & 0xFFFF0000u);
}
__device__ __forceinline__ f2 up2(u32 u) {
  f2 r;
  r.x = bflo(u);
  r.y = bfhi(u);
  return r;
}

// inclusive scan of lsum across 256 threads; wsum is 4-entry LDS scratch.
__device__ __forceinline__ int block_incl_scan(int lsum, int tid, int* wsum) {
  int lane = tid & 63, wv = tid >> 6;
  int v = lsum;
#pragma unroll
  for (int off = 1; off < 64; off <<= 1) {
    int t = __shfl_up(v, off, 64);
    if (lane >= off) v += t;
  }
  __syncthreads();
  if (lane == 63) wsum[wv] = v;
  __syncthreads();
  int add = 0;
  if (wv > 0) add += wsum[0];
  if (wv > 1) add += wsum[1];
  if (wv > 2) add += wsum[2];
  return v + add;
}

// ---------------- single-pass tile partition into padded bucket ------------

__global__ __launch_bounds__(256) void partition_direct(
    const int* __restrict__ rows, const int* __restrict__ cols, int nnz,
    int T, int* __restrict__ tcur, u32* __restrict__ bucket) {
  __shared__ u32 sorted[STAGE_CAP];
  __shared__ u16 sortedt[STAGE_CAP];
  __shared__ int cnt[TPAD], lstart[TPAD], gbase[TPAD];
  __shared__ int wsum[4];
  int w = blockIdx.x, tid = threadIdx.x;
  int rep = w & (NREP - 1);
  int j0 = tid * 3;
  cnt[j0] = 0; cnt[j0 + 1] = 0; cnt[j0 + 2] = 0;
  __syncthreads();
  int base = w * EWG;
  int end = min(base + EWG, nnz);
  int total = end - base;
  if (total <= 0) return;
  int nv = total >> 2;
  const int4* r4 = (const int4*)(rows + base);
  const int4* c4 = (const int4*)(cols + base);
  // pass 1: histogram rows; cache row int4s in registers for pass 2
  int4 rr[NI4];
#pragma unroll
  for (int j = 0; j < NI4; ++j) {
    int i = tid + j * 256;
    if (i < nv) {
      int4 r = r4[i];
      rr[j] = r;
      atomicAdd(&cnt[r.x >> TSHIFT], 1);
      atomicAdd(&cnt[r.y >> TSHIFT], 1);
      atomicAdd(&cnt[r.z >> TSHIFT], 1);
      atomicAdd(&cnt[r.w >> TSHIFT], 1);
    }
  }
  for (int e = base + (nv << 2) + tid; e < end; e += 256)
    atomicAdd(&cnt[rows[e] >> TSHIFT], 1);
  __syncthreads();
  int c0 = cnt[j0], c1 = cnt[j0 + 1], c2 = cnt[j0 + 2];
  int lsum = c0 + c1 + c2;
  int incl = block_incl_scan(lsum, tid, wsum);
  int excl = incl - lsum;
  lstart[j0] = excl;
  lstart[j0 + 1] = excl + c0;
  lstart[j0 + 2] = excl + c0 + c1;
  if (c0 > 0)
    gbase[j0] = j0 * TSTRIDE + rep * RSTR + atomicAdd(&tcur[j0 * NREP + rep], c0);
  if (c1 > 0)
    gbase[j0 + 1] = (j0 + 1) * TSTRIDE + rep * RSTR +
                    atomicAdd(&tcur[(j0 + 1) * NREP + rep], c1);
  if (c2 > 0)
    gbase[j0 + 2] = (j0 + 2) * TSTRIDE + rep * RSTR +
                    atomicAdd(&tcur[(j0 + 2) * NREP + rep], c2);
  cnt[j0] = 0; cnt[j0 + 1] = 0; cnt[j0 + 2] = 0;
  __syncthreads();
  // pass 2: rows from registers, cols from memory
#pragma unroll
  for (int j = 0; j < NI4; ++j) {
    int i = tid + j * 256;
    if (i < nv) {
      int4 r = rr[j];
      int4 c = c4[i];
      int t, s, d;
      t = r.x >> TSHIFT; s = atomicAdd(&cnt[t], 1); d = lstart[t] + s;
      sorted[d] = ((u32)(r.x & TMASK) << 18) | (u32)c.x; sortedt[d] = (u16)t;
      t = r.y >> TSHIFT; s = atomicAdd(&cnt[t], 1); d = lstart[t] + s;
      sorted[d] = ((u32)(r.y & TMASK) << 18) | (u32)c.y; sortedt[d] = (u16)t;
      t = r.z >> TSHIFT; s = atomicAdd(&cnt[t], 1); d = lstart[t] + s;
      sorted[d] = ((u32)(r.z & TMASK) << 18) | (u32)c.z; sortedt[d] = (u16)t;
      t = r.w >> TSHIFT; s = atomicAdd(&cnt[t], 1); d = lstart[t] + s;
      sorted[d] = ((u32)(r.w & TMASK) << 18) | (u32)c.w; sortedt[d] = (u16)t;
    }
  }
  for (int e = base + (nv << 2) + tid; e < end; e += 256) {
    int r = rows[e];
    int c = cols[e];
    int t = r >> TSHIFT;
    int s = atomicAdd(&cnt[t], 1);
    int d = lstart[t] + s;
    sorted[d] = ((u32)(r & TMASK) << 18) | (u32)c;
    sortedt[d] = (u16)t;
  }
  __syncthreads();
  for (int i = tid; i < total; i += 256) {
    int t = sortedt[i];
    bucket[(size_t)gbase[t] + (i - lstart[t])] = sorted[i];
  }
}

// ---------------- build: one block per 256-row tile, LDS-cached bucket -----

__global__ __launch_bounds__(256) void build_csr_y0(
    const u32* __restrict__ bucket, const int* __restrict__ tcur, int T,
    int U, int N, const float4* __restrict__ ue, const float4* __restrict__ ie,
    int* __restrict__ row_ptr, u32* __restrict__ csr,
    uint4* __restrict__ y0b) {
  __shared__ u32 ebuf[TSTRIDE];  // tile entries, compacted (<= 10240)
  __shared__ int tl[TPAD];
  __shared__ int hist[256];
  __shared__ int cur[256];
  __shared__ int wsum[4];
  int b = blockIdx.x;
  int t = (b & 1) ? (T - 1 - (b >> 1)) : (b >> 1);
  int tid = threadIdx.x;
  int j0 = tid * 3;
  int v0 = 0, v1 = 0, v2 = 0;
  if (j0 < T) {
    int4 q = ((const int4*)tcur)[j0];
    v0 = q.x + q.y + q.z + q.w;
  }
  if (j0 + 1 < T) {
    int4 q = ((const int4*)tcur)[j0 + 1];
    v1 = q.x + q.y + q.z + q.w;
  }
  if (j0 + 2 < T) {
    int4 q = ((const int4*)tcur)[j0 + 2];
    v2 = q.x + q.y + q.z + q.w;
  }
  int lsum = v0 + v1 + v2;
  int incl0 = block_incl_scan(lsum, tid, wsum);
  int excl0 = incl0 - lsum;
  tl[j0] = excl0 + v0;
  tl[j0 + 1] = excl0 + v0 + v1;
  tl[j0 + 2] = excl0 + v0 + v1 + v2;
  hist[tid] = 0;
  __syncthreads();
  int tbase = (t == 0) ? 0 : tl[t - 1];
  int4 rl = ((const int4*)tcur)[t];
  // single global pass: histogram + compact tile into LDS ebuf
  int off = 0;
#pragma unroll
  for (int rep = 0; rep < NREP; ++rep) {
    int len = (rep == 0) ? rl.x : (rep == 1) ? rl.y : (rep == 2) ? rl.z : rl.w;
    int rs = t * TSTRIDE + rep * RSTR;
    const uint4* b4 = (const uint4*)(bucket + rs);
    int nv = len >> 2;
    for (int i = tid; i < nv; i += 256) {
      uint4 e = b4[i];
      int d = off + (i << 2);
      ebuf[d] = e.x; ebuf[d + 1] = e.y; ebuf[d + 2] = e.z; ebuf[d + 3] = e.w;
      atomicAdd(&hist[e.x >> 18], 1);
      atomicAdd(&hist[e.y >> 18], 1);
      atomicAdd(&hist[e.z >> 18], 1);
      atomicAdd(&hist[e.w >> 18], 1);
    }
    for (int i = (nv << 2) + tid; i < len; i += 256) {
      u32 e = bucket[rs + i];
      ebuf[off + i] = e;
      atomicAdd(&hist[e >> 18], 1);
    }
    off += len;
  }
  int tlen = off;
  __syncthreads();
  int h = hist[tid];
  int incl = block_incl_scan(h, tid, wsum);
  int r = (t << TSHIFT) + tid;
  if (r < N) row_ptr[r + 1] = tbase + incl;
  if (t == 0 && tid == 0) row_ptr[0] = 0;
  if (b == 0 && tid < 8)  // zero sentinel row of y0b (spmm1 pads with it)
    y0b[(size_t)N * 8 + tid] = make_uint4(0, 0, 0, 0);
  cur[tid] = tbase + incl - h;
  __syncthreads();
  for (int pass = 0; pass < 8; ++pass) {
    int lr = pass * 32 + (tid >> 3);
    int q = tid & 7;
    int row = (t << TSHIFT) + lr;
    if (row < N) {
      float invs = rsqrtf((float)max(hist[lr], 1));
      const float4* src = (row < U) ? (ue + (size_t)row * 16 + q * 2)
                                    : (ie + (size_t)(row - U) * 16 + q * 2);
      float4 a = src[0], bb = src[1];
      uint4 o;
      o.x = f2bf(a.x * invs) | (f2bf(a.y * invs) << 16);
      o.y = f2bf(a.z * invs) | (f2bf(a.w * invs) << 16);
      o.z = f2bf(bb.x * invs) | (f2bf(bb.y * invs) << 16);
      o.w = f2bf(bb.z * invs) | (f2bf(bb.w * invs) << 16);
      y0b[(size_t)row * 8 + q] = o;
    }
  }
  // scatter entries into compact csr, from LDS
  for (int i = tid; i < tlen; i += 256) {
    u32 e = ebuf[i];
    csr[atomicAdd(&cur[e >> 18], 1)] = e & 0x3FFFFu;
  }
}

// ---------------- SpMM: 1 row / 8-lane group, 2-stage pipelined gathers ----

__device__ __forceinline__ void load_stage(
    u32 (&c)[8], uv4 (&g)[8], int k, int d, int s,
    const u32* __restrict__ csr, const char* __restrict__ yb, u32 soff,
    int n) {
#pragma unroll
  for (int j = 0; j < 8; ++j) c[j] = (k + j < d) ? csr[s + k + j] : (u32)n;
#pragma unroll
  for (int j = 0; j < 8; ++j)
    g[j] = *(const uv4*)(yb + (size_t)(((size_t)c[j] << 7) | soff));
}

#define ACC_STAGE(G)                                                         \
  _Pragma("unroll") for (int j = 0; j < 8; ++j) {                            \
    a0 += up2(G[j].x);                                                       \
    a1 += up2(G[j].y);                                                       \
    a2 += up2(G[j].z);                                                       \
    a3 += up2(G[j].w);                                                       \
  }

__global__ __launch_bounds__(256, 4) void spmm_sum(
    const int* __restrict__ row_ptr, const u32* __restrict__ csr,
    const u16* __restrict__ yin, u16* __restrict__ yout, int n) {
  if (blockIdx.x == 0 && threadIdx.x < 8)  // zero sentinel row of output
    ((uint4*)(yout + (size_t)n * DIM))[threadIdx.x] = make_uint4(0, 0, 0, 0);
  int row = (blockIdx.x * 256 + threadIdx.x) >> 3;
  int q8 = threadIdx.x & 7;
  if (row >= n) return;
  int s = row_ptr[row];
  int d = row_ptr[row + 1] - s;
  const char* yb = (const char*)yin;
  u32 soff = (u32)q8 << 4;
  f2 a0 = 0.f, a1 = 0.f, a2 = 0.f, a3 = 0.f;
  u32 cA[8], cB[8];
  uv4 gA[8], gB[8];
  if (d > 0) {
    load_stage(cA, gA, 0, d, s, csr, yb, soff, n);
    int k = 8;
    while (k < d) {
      load_stage(cB, gB, k, d, s, csr, yb, soff, n);
      k += 8;
      ACC_STAGE(gA)
      if (k >= d) {
        ACC_STAGE(gB)
        goto done;
      }
      load_stage(cA, gA, k, d, s, csr, yb, soff, n);
      k += 8;
      ACC_STAGE(gB)
    }
    ACC_STAGE(gA)
  }
done:;
  float inv = 1.0f / (float)max(d, 1);
  uint4 o;
  o.x = f2bf(a0.x * inv) | (f2bf(a0.y * inv) << 16);
  o.y = f2bf(a1.x * inv) | (f2bf(a1.y * inv) << 16);
  o.z = f2bf(a2.x * inv) | (f2bf(a2.y * inv) << 16);
  o.w = f2bf(a3.x * inv) | (f2bf(a3.y * inv) << 16);
  ((uint4*)(yout + (size_t)row * DIM))[q8] = o;
}

// ---------------- fused layer-3 + scorer (R21 one-wave-per-gather) ---------

#define ACC8(G)                                                              \
  s0 += bflo(G.x); s1 += bfhi(G.x);                                          \
  s2 += bflo(G.y); s3 += bfhi(G.y);                                          \
  s4 += bflo(G.z); s5 += bfhi(G.z);                                          \
  s6 += bflo(G.w); s7 += bfhi(G.w);

__device__ __forceinline__ void gather8(
    const int* __restrict__ row_ptr, const u32* __restrict__ csr,
    const u16* __restrict__ y, int row, int s, int q8, int n, float* o) {
  int start = row_ptr[row];
  int end = row_ptr[row + 1];
  float s0 = 0.f, s1 = 0.f, s2 = 0.f, s3 = 0.f;
  float s4 = 0.f, s5 = 0.f, s6 = 0.f, s7 = 0.f;
  for (int k = start + s; k < end; k += 16) {
    int k2 = k + 8;
    bool ok2 = k2 < end;
    u32 c0 = csr[k];
    u32 c1 = ok2 ? csr[k2] : (u32)n;
    uint4 g0 = ((const uint4*)(y + (size_t)c0 * DIM))[q8];
    uint4 g1 = ((const uint4*)(y + (size_t)c1 * DIM))[q8];
    ACC8(g0) ACC8(g1)
  }
  for (int m = 8; m <= 32; m <<= 1) {
    s0 += __shfl_xor(s0, m, 64); s1 += __shfl_xor(s1, m, 64);
    s2 += __shfl_xor(s2, m, 64); s3 += __shfl_xor(s3, m, 64);
    s4 += __shfl_xor(s4, m, 64); s5 += __shfl_xor(s5, m, 64);
    s6 += __shfl_xor(s6, m, 64); s7 += __shfl_xor(s7, m, 64);
  }
  o[0] = s0; o[1] = s1; o[2] = s2; o[3] = s3;
  o[4] = s4; o[5] = s5; o[6] = s6; o[7] = s7;
}

// 2 pairs/block; 2 waves/pair (wave0=user row, wave1=item row). Each wave
// builds its side's full 64-dim vector into LDS; wave0 does the dot.
__global__ __launch_bounds__(256) void spmm3_score(
    const int* __restrict__ row_ptr, const u32* __restrict__ csr,
    const float* __restrict__ ue, const float* __restrict__ ie,
    const u16* __restrict__ y1b, const u16* __restrict__ y2b,
    const int* __restrict__ user_ids, const int* __restrict__ item_ids,
    int U, int N, int batch, float* __restrict__ out) {
  __shared__ float ab[2][2][64];  // [pair-in-block][side][dim]
  int tid = threadIdx.x;
  int pl = tid >> 7;              // pair slot in block (0,1)
  int side = (tid >> 6) & 1;      // 0=user, 1=item
  int lane = tid & 63;
  int w = blockIdx.x * 2 + pl;
  bool active = w < batch;
  int s = lane >> 3;
  int q8 = lane & 7;
  if (active) {
    int u = user_ids[w];
    int iti = item_ids[w];
    int row = (side == 0) ? u : iti + U;
    float g[8];
    gather8(row_ptr, csr, y2b, row, s, q8, N, g);
    int dd = row_ptr[row + 1] - row_ptr[row];
    float sd = sqrtf((float)max(dd, 1)), rd = 1.0f / sd;
    const float4* pe = (side == 0)
                           ? (const float4*)(ue + (size_t)u * DIM) + q8 * 2
                           : (const float4*)(ie + (size_t)iti * DIM) + q8 * 2;
    float4 ea = pe[0], eb = pe[1];
    uint4 y1v = ((const uint4*)(y1b + (size_t)row * DIM))[q8];
    uint4 y2v = ((const uint4*)(y2b + (size_t)row * DIM))[q8];
    if (s == 0) {  // one writer per q8 (all s-lanes hold identical g)
      float* dst = &ab[pl][side][q8 * 8];
      dst[0] = ea.x + sd * (bflo(y1v.x) + bflo(y2v.x)) + rd * g[0];
      dst[1] = ea.y + sd * (bfhi(y1v.x) + bfhi(y2v.x)) + rd * g[1];
      dst[2] = ea.z + sd * (bflo(y1v.y) + bflo(y2v.y)) + rd * g[2];
      dst[3] = ea.w + sd * (bfhi(y1v.y) + bfhi(y2v.y)) + rd * g[3];
      dst[4] = eb.x + sd * (bflo(y1v.z) + bflo(y2v.z)) + rd * g[4];
      dst[5] = eb.y + sd * (bfhi(y1v.z) + bfhi(y2v.z)) + rd * g[5];
      dst[6] = eb.z + sd * (bflo(y1v.w) + bflo(y2v.w)) + rd * g[6];
      dst[7] = eb.w + sd * (bfhi(y1v.w) + bfhi(y2v.w)) + rd * g[7];
    }
  }
  __syncthreads();
  if (active && side == 0) {
    float p = ab[pl][0][lane] * ab[pl][1][lane];
    p += __shfl_xor(p, 1, 64);
    p += __shfl_xor(p, 2, 64);
    p += __shfl_xor(p, 4, 64);
    p += __shfl_xor(p, 8, 64);
    p += __shfl_xor(p, 16, 64);
    p += __shfl_xor(p, 32, 64);
    if (lane == 0) out[w] = p * (1.0f / 16.0f);
  }
}

extern "C" void kernel_launch(void* const* d_in, const int* in_sizes, int n_in,
                              void* d_out, int out_size, void* d_ws, size_t ws_size,
                              hipStream_t stream) {
  const float* user_emb = (const float*)d_in[0];
  const float* item_emb = (const float*)d_in[1];
  const int* adj_rows = (const int*)d_in[3];
  const int* adj_cols = (const int*)d_in[4];
  const int* user_ids = (const int*)d_in[5];
  const int* item_ids = (const int*)d_in[6];
  float* scores = (float*)d_out;

  const int U = in_sizes[0] / DIM;  // 100000
  const int I = in_sizes[1] / DIM;  // 50000
  const int N = U + I;              // 150000
  const int nnz = in_sizes[2];      // 3200000
  const int B = in_sizes[5];        // 4096

  const int T = (N + TMASK) >> TSHIFT;    // 586
  const int npw = (nnz + EWG - 1) / EWG;  // 511

  char* p = (char*)d_ws;
  auto carve = [&](size_t bytes) {
    void* r = (void*)p;
    p += (bytes + 255) & ~(size_t)255;
    return r;
  };
  u16* y0b = (u16*)carve((size_t)(N + 1) * DIM * 2);
  u16* y1b = (u16*)carve((size_t)(N + 1) * DIM * 2);
  u16* y2b = (u16*)carve((size_t)(N + 1) * DIM * 2);
  int* row_ptr = (int*)carve((size_t)(N + 1) * 4);
  int* tcur = (int*)carve((size_t)T * NREP * 4);
  u32* bucket = (u32*)carve((size_t)(T + 1) * TSTRIDE * 4);
  u32* csr = (u32*)carve((size_t)nnz * 4);

  hipMemsetAsync(tcur, 0, (size_t)T * NREP * 4, stream);

  partition_direct<<<npw, 256, 0, stream>>>(adj_rows, adj_cols, nnz, T, tcur,
                                            bucket);

  build_csr_y0<<<T, 256, 0, stream>>>(bucket, tcur, T, U, N,
                                      (const float4*)user_emb,
                                      (const float4*)item_emb, row_ptr,
                                      csr, (uint4*)y0b);

  const int sblocks = (N * 8 + 255) / 256;  // 8 lanes per row
  spmm_sum<<<sblocks, 256, 0, stream>>>(row_ptr, csr, y0b, y1b, N);
  spmm_sum<<<sblocks, 256, 0, stream>>>(row_ptr, csr, y1b, y2b, N);

  spmm3_score<<<(B + 1) / 2, 256, 0, stream>>>(row_ptr, csr, user_emb,
                                               item_emb, y1b, y2b, user_ids,
                                               item_ids, U, N, B, scores);
}